// Round 1
// 503.721 us; speedup vs baseline: 1.9165x; 1.9165x over previous
//
#include <hip/hip_runtime.h>

#define BB 256
#define NN 512
#define FF 10
#define HH 32

// One block = one (batch, 32-row tile). 16 tiles per batch.
// LDS: s[b] (512x10), k half-tile (256 x pad36), q tile (32 x pad36), weights.
// Total = 20480 + 36864 + 4608 + 2560 = 64512 B -> 2 blocks/CU on 160 KiB LDS.
//
// R1 fix: previous version indexed the score accumulator as sc[r][pass*4+c]
// inside a NON-unrolled pass loop -> runtime index -> sc[8][8] demoted to
// SCRATCH (rule #20). Evidence: VGPR=88 (can't hold g[64]+sc[64]),
// WRITE_SIZE 1.49 GB vs 268 MB output (5.6x), VALUBusy 12%. Fix: two named
// register arrays scA/scB, passes expanded with compile-time indices only.

// Pass body: build k half-tile for rows [J0, J0+256) in LDS, then accumulate
// this wave's 8x4 score sub-block into SC (all indices compile-time).
#define PASS_BODY(J0, SC)                                                     \
    do {                                                                      \
        __syncthreads(); /* pass0: q_lds ready; pass1: k_lds reuse gate */    \
        {                                                                     \
            const int m  = t & 31;                                            \
            const int jg = t >> 5; /* 0..7 */                                 \
            for (int i = 0; i < 32; ++i) {                                    \
                const int j = jg * 32 + i; /* local 0..255 */                 \
                float acc = 0.f;                                              \
                _Pragma("unroll")                                             \
                for (int f = 0; f < FF; ++f)                                  \
                    acc += s_lds[((J0) + j) * FF + f] * kw_lds[f * HH + m];   \
                k_lds[j * 36 + m] = acc;                                      \
            }                                                                 \
        }                                                                     \
        __syncthreads();                                                      \
        _Pragma("unroll")                                                     \
        for (int mc = 0; mc < 8; ++mc) {                                      \
            float4 kf[4];                                                     \
            _Pragma("unroll")                                                 \
            for (int c = 0; c < 4; ++c)                                       \
                kf[c] = *(const float4*)&k_lds[(lane + 64 * c) * 36 + mc * 4];\
            _Pragma("unroll")                                                 \
            for (int r = 0; r < 8; ++r) {                                     \
                const float4 q4 =                                             \
                    *(const float4*)&q_lds[(r0 + r) * 36 + mc * 4];           \
                _Pragma("unroll")                                             \
                for (int c = 0; c < 4; ++c) {                                 \
                    SC[r][c] += q4.x * kf[c].x + q4.y * kf[c].y               \
                              + q4.z * kf[c].z + q4.w * kf[c].w;              \
                }                                                             \
            }                                                                 \
        }                                                                     \
    } while (0)

__global__ __launch_bounds__(256, 2)
void att_kernel(const float* __restrict__ s,
                const float* __restrict__ G,
                const float* __restrict__ Qw,
                const float* __restrict__ Kw,
                float* __restrict__ out) {
    __shared__ float s_lds[NN * FF];        // 20480 B
    __shared__ float k_lds[256 * 36];       // 36864 B (stride 36: 16B-aligned rows)
    __shared__ float q_lds[32 * 36];        // 4608 B
    __shared__ float qw_lds[FF * HH];       // 1280 B
    __shared__ float kw_lds[FF * HH];       // 1280 B

    const int t    = threadIdx.x;
    const int b    = blockIdx.x >> 4;
    const int tile = blockIdx.x & 15;
    const int row0 = tile * 32;
    const int wave = t >> 6;                // 0..3
    const int lane = t & 63;
    const int r0   = wave * 8;              // wave's first local row

    // ---- prefetch this wave's Gmat values (8 rows x 8 chunks) -------------
    // Issued first: 268 MB of HBM reads overlap the whole compute phase.
    float g[8][8];
    const float* Gb = G + (size_t)b * NN * NN;
    #pragma unroll
    for (int r = 0; r < 8; ++r) {
        const float* gp = Gb + (size_t)(row0 + r0 + r) * NN + lane;
        #pragma unroll
        for (int c = 0; c < 8; ++c) g[r][c] = gp[64 * c];
    }

    // ---- stage s[b] and weights into LDS (coalesced) ----------------------
    const float* sb = s + (size_t)b * NN * FF;
    for (int i = t; i < NN * FF; i += 256) s_lds[i] = sb[i];
    for (int i = t; i < FF * HH; i += 256) { qw_lds[i] = Qw[i]; kw_lds[i] = Kw[i]; }
    __syncthreads();

    // ---- q for the block's 32 rows ----------------------------------------
    {
        const int m = t & 31;
        const int rg = t >> 5;              // 0..7
        #pragma unroll
        for (int rr = 0; rr < 4; ++rr) {
            const int rl = rg + 8 * rr;     // 0..31
            float acc = 0.f;
            #pragma unroll
            for (int f = 0; f < FF; ++f)
                acc += s_lds[(row0 + rl) * FF + f] * qw_lds[f * HH + m];
            q_lds[rl * 36 + m] = acc;
        }
    }

    // ---- score accumulators: two named 8x4 register arrays ----------------
    float scA[8][4], scB[8][4];
    #pragma unroll
    for (int r = 0; r < 8; ++r)
        #pragma unroll
        for (int c = 0; c < 4; ++c) { scA[r][c] = 0.f; scB[r][c] = 0.f; }

    // ---- two j-half passes, expanded (no runtime pass index anywhere) -----
    PASS_BODY(0,   scA);   // columns lane + 64c,        c = 0..3
    PASS_BODY(256, scB);   // columns 256 + lane + 64c,  c = 0..3

    // ---- epilogue: att = sc^2 * g; row-normalize; store --------------------
    float* ob = out + (size_t)b * NN * NN;
    #pragma unroll
    for (int r = 0; r < 8; ++r) {
        float a[8];
        float rs = 0.f;
        #pragma unroll
        for (int c = 0; c < 4; ++c) {
            float v = scA[r][c];
            v = v * v * g[r][c];
            a[c] = v;
            rs += v;
        }
        #pragma unroll
        for (int c = 0; c < 4; ++c) {
            float v = scB[r][c];
            v = v * v * g[r][4 + c];
            a[4 + c] = v;
            rs += v;
        }
        #pragma unroll
        for (int off = 32; off > 0; off >>= 1) rs += __shfl_xor(rs, off, 64);
        const float inv = 1.0f / (rs + 0.001f);
        float* op = ob + (size_t)(row0 + r0 + r) * NN + lane;
        #pragma unroll
        for (int c = 0; c < 8; ++c) op[64 * c] = a[c] * inv;
    }
}

extern "C" void kernel_launch(void* const* d_in, const int* in_sizes, int n_in,
                              void* d_out, int out_size, void* d_ws, size_t ws_size,
                              hipStream_t stream) {
    const float* s  = (const float*)d_in[0];
    const float* G  = (const float*)d_in[1];
    const float* Qw = (const float*)d_in[2];
    const float* Kw = (const float*)d_in[3];
    float* out = (float*)d_out;
    dim3 grid(BB * 16);   // 16 row-tiles per batch
    dim3 block(256);
    att_kernel<<<grid, block, 0, stream>>>(s, G, Qw, Kw, out);
}

// Round 2
// 472.258 us; speedup vs baseline: 2.0442x; 1.0666x over previous
//
#include <hip/hip_runtime.h>

#define BB 256
#define NN 512
#define FF 10
#define HH 32

// R2 restructure: scores = q k^T = s (Qw Kw^T) s^T = t s^T with M = Qw Kw^T
// (10x10), t = s M (512x10 per batch). Kills the k-tile (37 KB LDS + rebuild
// FMAs + 2 barriers) and cuts the score dot product K=32 -> K=10.
// Block = 512 threads (8 waves), one (batch, 32-row tile); wave owns 4 rows,
// lane owns cols {lane + 64c}. LDS ~25.7 KB -> occupancy VGPR-capped at
// 4 waves/SIMD via __launch_bounds__(512,4).
// All accumulator indices compile-time (rule #20): halves expanded by macro.

#define HALF_BODY(CC, SC)                                                     \
    do {                                                                      \
        float sj[4][FF];                                                      \
        _Pragma("unroll")                                                     \
        for (int c4 = 0; c4 < 4; ++c4) {                                      \
            const int j = lane + 64 * ((CC) * 4 + c4);                        \
            _Pragma("unroll")                                                 \
            for (int f = 0; f < FF; ++f) sj[c4][f] = st_lds[f][j];            \
        }                                                                     \
        _Pragma("unroll")                                                     \
        for (int r = 0; r < 4; ++r) {                                         \
            const float4 t0 = *(const float4*)&t_lds[r0 + r][0];              \
            const float4 t1 = *(const float4*)&t_lds[r0 + r][4];              \
            const float2 t2 = *(const float2*)&t_lds[r0 + r][8];              \
            _Pragma("unroll")                                                 \
            for (int c4 = 0; c4 < 4; ++c4) {                                  \
                SC[r][c4] += t0.x * sj[c4][0] + t0.y * sj[c4][1]              \
                           + t0.z * sj[c4][2] + t0.w * sj[c4][3]              \
                           + t1.x * sj[c4][4] + t1.y * sj[c4][5]              \
                           + t1.z * sj[c4][6] + t1.w * sj[c4][7]              \
                           + t2.x * sj[c4][8] + t2.y * sj[c4][9];             \
            }                                                                 \
        }                                                                     \
    } while (0)

__global__ __launch_bounds__(512, 4)
void att_kernel(const float* __restrict__ s,
                const float* __restrict__ G,
                const float* __restrict__ Qw,
                const float* __restrict__ Kw,
                float* __restrict__ out) {
    __shared__ float st_lds[FF][NN];     // transposed s: [f][j], 20480 B
    __shared__ float t_lds[32][12];      // t rows of this tile, 16B-aligned rows
    __shared__ float m_lds[FF][FF];      // M = Qw Kw^T
    __shared__ float qw_lds[FF * HH];
    __shared__ float kw_lds[FF * HH];

    const int t    = threadIdx.x;
    const int b    = blockIdx.x >> 4;
    const int tile = blockIdx.x & 15;
    const int row0 = tile * 32;
    const int wave = t >> 6;             // 0..7
    const int lane = t & 63;
    const int r0   = wave * 4;           // wave's first local row

    // ---- stage s (transposed) and weights ---------------------------------
    const float* sb = s + (size_t)b * NN * FF;
    for (int i = t; i < NN * FF; i += 512) {
        const int j = i / FF, f = i % FF;
        st_lds[f][j] = sb[i];
    }
    if (t < FF * HH) { qw_lds[t] = Qw[t]; kw_lds[t] = Kw[t]; }
    __syncthreads();

    // ---- M[f][f2] = sum_m Qw[f][m] Kw[f2][m] ------------------------------
    if (t < FF * FF) {
        const int f = t / FF, f2 = t % FF;
        float acc = 0.f;
        #pragma unroll
        for (int m = 0; m < HH; ++m)
            acc += qw_lds[f * HH + m] * kw_lds[f2 * HH + m];
        m_lds[f][f2] = acc;
    }
    __syncthreads();

    // ---- t[rl][f2] = sum_f s[row0+rl][f] * M[f][f2] -----------------------
    if (t < 32 * FF) {
        const int rl = t / FF, f2 = t % FF;
        float acc = 0.f;
        #pragma unroll
        for (int f = 0; f < FF; ++f)
            acc += st_lds[f][row0 + rl] * m_lds[f][f2];
        t_lds[rl][f2] = acc;
    }
    __syncthreads();

    // ---- scores: sc[r][c] = t_row . s_col (K = 10) ------------------------
    float scA[4][4], scB[4][4];
    #pragma unroll
    for (int r = 0; r < 4; ++r)
        #pragma unroll
        for (int c = 0; c < 4; ++c) { scA[r][c] = 0.f; scB[r][c] = 0.f; }

    HALF_BODY(0, scA);   // cols lane + 64c,        c = 0..3
    HALF_BODY(1, scB);   // cols 256 + lane + 64c,  c = 0..3

    // ---- epilogue: att = sc^2 * G; row-normalize; store -------------------
    const float* Gb = G + (size_t)b * NN * NN;
    float* ob = out + (size_t)b * NN * NN;
    #pragma unroll
    for (int r = 0; r < 4; ++r) {
        const size_t rowoff = (size_t)(row0 + r0 + r) * NN + lane;
        const float* gp = Gb + rowoff;
        float a[8];
        float rs = 0.f;
        #pragma unroll
        for (int c = 0; c < 4; ++c) {
            float v = scA[r][c];
            v = v * v * gp[64 * c];
            a[c] = v; rs += v;
        }
        #pragma unroll
        for (int c = 0; c < 4; ++c) {
            float v = scB[r][c];
            v = v * v * gp[256 + 64 * c];
            a[4 + c] = v; rs += v;
        }
        #pragma unroll
        for (int off = 32; off > 0; off >>= 1) rs += __shfl_xor(rs, off, 64);
        const float inv = 1.0f / (rs + 0.001f);
        float* op = ob + rowoff;
        #pragma unroll
        for (int c = 0; c < 4; ++c) op[64 * c] = a[c] * inv;
        #pragma unroll
        for (int c = 0; c < 4; ++c) op[256 + 64 * c] = a[4 + c] * inv;
    }
}

extern "C" void kernel_launch(void* const* d_in, const int* in_sizes, int n_in,
                              void* d_out, int out_size, void* d_ws, size_t ws_size,
                              hipStream_t stream) {
    const float* s  = (const float*)d_in[0];
    const float* G  = (const float*)d_in[1];
    const float* Qw = (const float*)d_in[2];
    const float* Kw = (const float*)d_in[3];
    float* out = (float*)d_out;
    dim3 grid(BB * 16);   // 16 row-tiles per batch
    dim3 block(512);
    att_kernel<<<grid, block, 0, stream>>>(s, G, Qw, Kw, out);
}